// Round 15
// baseline (124.734 us; speedup 1.0000x reference)
//
#include <hip/hip_runtime.h>
#include <math.h>
#include <stdint.h>

#define B_ 4
#define S_ 2048
#define DM_ 1024
#define DK_ 128

static constexpr float SCALE = 0.08838834764831845f; // 1/sqrt(128)

typedef __attribute__((ext_vector_type(8))) short short8;
typedef __attribute__((ext_vector_type(4))) float f32x4;
typedef __attribute__((ext_vector_type(4))) unsigned short us4;

__device__ __forceinline__ unsigned enc_f32(float f){
  unsigned u = __float_as_uint(f);
  return (u & 0x80000000u) ? ~u : (u | 0x80000000u);
}
__device__ __forceinline__ float dec_f32(unsigned u){
  unsigned v = (u & 0x80000000u) ? (u & 0x7FFFFFFFu) : ~u;
  return __uint_as_float(v);
}
__device__ __forceinline__ unsigned short bf16rne(float f){
  unsigned u = __float_as_uint(f);
  unsigned r = (u + 0x7FFFu + ((u>>16)&1u)) >> 16;
  return (unsigned short)r;
}
__device__ __forceinline__ float bf16tof(unsigned short h){
  return __uint_as_float((unsigned)h << 16);
}
// async global->LDS, 16B per lane; LDS dest = wave-uniform base + lane*16
__device__ __forceinline__ void gload16(const void* g, void* l){
  __builtin_amdgcn_global_load_lds(
      (const __attribute__((address_space(1))) void*)g,
      (__attribute__((address_space(3))) void*)l, 16, 0, 0);
}

// ---- init: column-max to enc(-inf) ----
__global__ __launch_bounds__(256) void init_kernel(unsigned* __restrict__ cmax){
  int i = blockIdx.x*256 + threadIdx.x;
  if(i < B_*S_) cmax[i] = 0x007FFFFFu; // enc(-INF)
}

// ---- X pre-convert: f32 [8192][1024] -> bf16 hi/lo MFMA-fragment image
//      image unit (mb,kt,g,row): 8 shorts = X[mb*32+row][kt*32+g*8 ..+8]  ----
__global__ __launch_bounds__(256) void xconv_kernel(
    const float* __restrict__ X,
    unsigned short* __restrict__ Xth, unsigned short* __restrict__ Xtl)
{
  const int kt = blockIdx.x & 31, mb = blockIdx.x >> 5;
  const int tid = threadIdx.x;
  const int unit = tid & 127, half = tid >> 7;
  const int g = unit >> 5, row = unit & 31;
  const float* src = X + (size_t)(mb*32 + row)*DM_ + kt*32 + g*8;
  float4 a = *reinterpret_cast<const float4*>(src);
  float4 b = *reinterpret_cast<const float4*>(src + 4);
  unsigned short* dst = (half ? Xtl : Xth) + ((size_t)(mb*32 + kt)*128 + unit)*8;
  if(half == 0){
    us4 h0 = {bf16rne(a.x),bf16rne(a.y),bf16rne(a.z),bf16rne(a.w)};
    us4 h1 = {bf16rne(b.x),bf16rne(b.y),bf16rne(b.z),bf16rne(b.w)};
    *(us4*)dst = h0; *(us4*)(dst+4) = h1;
  } else {
    us4 l0 = {bf16rne(a.x - bf16tof(bf16rne(a.x))), bf16rne(a.y - bf16tof(bf16rne(a.y))),
              bf16rne(a.z - bf16tof(bf16rne(a.z))), bf16rne(a.w - bf16tof(bf16rne(a.w)))};
    us4 l1 = {bf16rne(b.x - bf16tof(bf16rne(b.x))), bf16rne(b.y - bf16tof(bf16rne(b.y))),
              bf16rne(b.z - bf16tof(bf16rne(b.z))), bf16rne(b.w - bf16tof(bf16rne(b.w)))};
    *(us4*)dst = l0; *(us4*)(dst+4) = l1;
  }
}

// ---- W pre-convert: f32 [1024][128] -> bf16 hi/lo, pre-tiled [32 t][col][40] ----
__global__ __launch_bounds__(256) void wconv_kernel(
    const float* __restrict__ Wq, const float* __restrict__ Wk, const float* __restrict__ Wv,
    unsigned short* __restrict__ Wth, unsigned short* __restrict__ Wtl)
{
  const int t = blockIdx.x;       // k-tile 0..31
  const int which = blockIdx.y;   // 0..2
  const float* W = (which==0) ? Wq : ((which==1) ? Wk : Wv);
  const int tid = threadIdx.x;
  const size_t obase = ((size_t)which*32 + t)*5120;
  #pragma unroll
  for(int it=0; it<2; ++it){
    int idx = tid + 256*it;       // 0..511 -> (col, g)
    int col = idx & 127, g = idx >> 7;
    unsigned short hs[8], ls[8];
    #pragma unroll
    for(int j=0;j<8;j++){
      float f = W[(size_t)(t*32 + g*8 + j)*DK_ + col];
      unsigned short h = bf16rne(f);
      hs[j] = h;
      ls[j] = bf16rne(f - bf16tof(h));
    }
    size_t o = obase + (size_t)col*40 + g*8;
    *(us4*)&Wth[o]   = us4{hs[0],hs[1],hs[2],hs[3]};
    *(us4*)&Wth[o+4] = us4{hs[4],hs[5],hs[6],hs[7]};
    *(us4*)&Wtl[o]   = us4{ls[0],ls[1],ls[2],ls[3]};
    *(us4*)&Wtl[o+4] = us4{ls[4],ls[5],ls[6],ls[7]};
  }
}

// ---- QKV GEMM v8: bf16x3 MFMA, M=32; A and B both via global_load_lds dbuf;
//      ONE barrier per K-tile, zero in-loop VALU conversion ----
__global__ __launch_bounds__(256) void qkv_mfma_kernel(
    const unsigned short* __restrict__ Xth, const unsigned short* __restrict__ Xtl,
    const unsigned short* __restrict__ Wth, const unsigned short* __restrict__ Wtl,
    unsigned short* __restrict__ Qh, unsigned short* __restrict__ Ql,
    unsigned short* __restrict__ Kh, unsigned short* __restrict__ Kl,
    unsigned short* __restrict__ Vth, unsigned short* __restrict__ Vtl)
{
  // bytes: bufA(buf) = buf*4096 : [Ah 2KB][Al 2KB]
  //        bufB(buf) = 8192 + buf*20480 : [Bh 10KB][Bl 10KB]    total 48KB
  __shared__ __align__(16) unsigned char smem[49152];
  const int tid = threadIdx.x;
  const int w = tid >> 6, lane = tid & 63;
  const int l15 = lane & 15, g = lane >> 4;
  const int which = blockIdx.y;
  const int m0 = blockIdx.x * 32;
  const int mb = blockIdx.x;
  const unsigned char* Wh8 = (const unsigned char*)(Wth + (size_t)which*32*5120);
  const unsigned char* Wl8 = (const unsigned char*)(Wtl + (size_t)which*32*5120);
  // A granule source: wave w -> {h g0, h g1, l g0, l g1}
  const unsigned short* Asrc = ((w < 2) ? Xth : Xtl) + (size_t)(mb*32)*1024 + (w & 1)*512 + lane*8;
  const unsigned Adst = (unsigned)((w & 1)*1024) + ((w < 2) ? 0u : 2048u);

  // prologue: tile 0 -> buf0
  gload16(Asrc, smem + Adst + lane*0 /*dest base*/ );   // note: dest = base + lane*16 implicit
  #pragma unroll
  for(int ii=0; ii<5; ++ii){
    int i = w + 4*ii;
    const unsigned char* src = (i<10) ? (Wh8 + i*1024) : (Wl8 + (i-10)*1024);
    unsigned dst = 8192u + ((i<10) ? (unsigned)i*1024u : 10240u + (unsigned)(i-10)*1024u);
    gload16(src + lane*16, smem + dst);
  }

  f32x4 acc[4] = {f32x4{0,0,0,0},f32x4{0,0,0,0},f32x4{0,0,0,0},f32x4{0,0,0,0}};
  const int r = w >> 1, c0 = (w & 1)*4;   // wave -> (row-tile, col-tile base)
  const int aoff = (g*32 + r*16 + l15)*8; // shorts, within Ah/Al (unit = g*32+row)
  int buf = 0;
  for(int t=0; t<32; ++t){
    __syncthreads();            // drains vmcnt -> tile t (buf) ready; buf^1 free
    if(t+1 < 32){               // issue tile t+1 -> buf^1
      gload16(Asrc + (size_t)(t+1)*1024, smem + (buf^1)*4096 + Adst);
      const unsigned char* WhT = Wh8 + (size_t)(t+1)*10240;
      const unsigned char* WlT = Wl8 + (size_t)(t+1)*10240;
      unsigned bbase = 8192u + (unsigned)(buf^1)*20480u;
      #pragma unroll
      for(int ii=0; ii<5; ++ii){
        int i = w + 4*ii;
        const unsigned char* src = (i<10) ? (WhT + i*1024) : (WlT + (i-10)*1024);
        unsigned dst = bbase + ((i<10) ? (unsigned)i*1024u : 10240u + (unsigned)(i-10)*1024u);
        gload16(src + lane*16, smem + dst);
      }
    }
    const unsigned short* Ab = (const unsigned short*)(smem + buf*4096);
    const unsigned short* Bhc = (const unsigned short*)(smem + 8192 + buf*20480);
    const unsigned short* Blc = Bhc + 5120;
    short8 ah = *(const short8*)&Ab[aoff];
    short8 al = *(const short8*)&Ab[1024 + aoff];
    #pragma unroll
    for(int c=0;c<4;c++){
      int boff = ((c0+c)*16 + l15)*40 + g*8;
      short8 bh = *(const short8*)&Bhc[boff];
      short8 bl = *(const short8*)&Blc[boff];
      acc[c] = __builtin_amdgcn_mfma_f32_16x16x32_bf16(ah, bh, acc[c], 0, 0, 0);
      acc[c] = __builtin_amdgcn_mfma_f32_16x16x32_bf16(ah, bl, acc[c], 0, 0, 0);
      acc[c] = __builtin_amdgcn_mfma_f32_16x16x32_bf16(al, bh, acc[c], 0, 0, 0);
    }
    buf ^= 1;
  }
  // epilogue: C layout col=lane&15, row=(lane>>4)*4+reg  [verified m89/m91]
  const int b = m0 >> 11;
  const int orow0 = g*4;
  if(which != 2){
    unsigned short* Oh = (which==0) ? Qh : Kh;
    unsigned short* Ol = (which==0) ? Ql : Kl;
    #pragma unroll
    for(int c=0;c<4;c++){
      int col = (c0+c)*16 + l15;
      #pragma unroll
      for(int j=0;j<4;j++){
        float f = acc[c][j];
        unsigned short h = bf16rne(f);
        unsigned short lo = bf16rne(f - bf16tof(h));
        size_t o = (size_t)(m0 + r*16 + orow0 + j)*DK_ + col;
        Oh[o] = h; Ol[o] = lo;
      }
    }
  } else {
    // V: transpose through LDS, store bf16 hi/lo as Vt[b][d][s]
    __syncthreads();
    float* Tmp = (float*)smem;                 // [32][133] = 17KB
    #pragma unroll
    for(int c=0;c<4;c++){
      int col = (c0+c)*16 + l15;
      #pragma unroll
      for(int j=0;j<4;j++)
        Tmp[(r*16 + orow0 + j)*133 + col] = acc[c][j];
    }
    __syncthreads();
    const int s0 = m0 & (S_-1);
    #pragma unroll
    for(int l2=0;l2<16;l2++){
      int p = tid + 256*l2;                    // 4096 elems: 128 d x 32 rows
      int d = p >> 5, rr = p & 31;
      float f = Tmp[rr*133 + d];
      unsigned short h = bf16rne(f);
      Vth[(size_t)(b*DK_ + d)*S_ + s0 + rr] = h;
      Vtl[(size_t)(b*DK_ + d)*S_ + s0 + rr] = bf16rne(f - bf16tof(h));
    }
  }
}

// ---- scores via bf16x3 MFMA: raw s (masked=0) -> attn; column max ----
__global__ __launch_bounds__(256) void scores_kernel(
    const unsigned short* __restrict__ Qh, const unsigned short* __restrict__ Ql,
    const unsigned short* __restrict__ Kh, const unsigned short* __restrict__ Kl,
    float* __restrict__ attn, unsigned* __restrict__ cmax)
{
  const int tj = blockIdx.x, ti = blockIdx.y, b = blockIdx.z;
  const int tid = threadIdx.x;
  const int q0 = ti*64, k0 = tj*64;
  if(tj > ti){                                 // upper triangle: zero-fill tile
    float4 z = {0.f,0.f,0.f,0.f};
    #pragma unroll
    for(int l=0;l<4;l++){
      int p = tid + 256*l;
      int r = p >> 4, c = (p & 15) << 2;
      *reinterpret_cast<float4*>(&attn[((size_t)(b*S_) + q0 + r)*S_ + k0 + c]) = z;
    }
    return;
  }
  __shared__ __align__(16) unsigned short sm[18432];   // 4 x [64][72]
  __shared__ float cred[16][64];
  unsigned short* Qhs = sm;
  unsigned short* Qls = sm + 4608;
  unsigned short* Khs = sm + 9216;
  unsigned short* Kls = sm + 13824;
  const int w = tid >> 6, lane = tid & 63, l15 = lane & 15, g = lane >> 4;
  f32x4 acc[4] = {f32x4{0,0,0,0},f32x4{0,0,0,0},f32x4{0,0,0,0},f32x4{0,0,0,0}};
  for(int kh=0; kh<2; ++kh){
    __syncthreads();                           // prev compute readers done
    #pragma unroll
    for(int l=0;l<2;l++){                      // stage 4 tiles (this K-half)
      int p = tid + 256*l;
      int row = p >> 3, cc = p & 7;
      size_t gq = (size_t)(b*S_ + q0 + row)*DK_ + kh*64 + cc*8;
      size_t gk = (size_t)(b*S_ + k0 + row)*DK_ + kh*64 + cc*8;
      int lo_ = row*72 + cc*8;
      *(short8*)&Qhs[lo_] = *(const short8*)&Qh[gq];
      *(short8*)&Qls[lo_] = *(const short8*)&Ql[gq];
      *(short8*)&Khs[lo_] = *(const short8*)&Kh[gk];
      *(short8*)&Kls[lo_] = *(const short8*)&Kl[gk];
    }
    __syncthreads();
    #pragma unroll
    for(int ks=0; ks<2; ++ks){                 // 2 x K=32 per half
      int ao = (w*16 + l15)*72 + ks*32 + g*8;
      short8 ah = *(const short8*)&Qhs[ao];
      short8 al = *(const short8*)&Qls[ao];
      #pragma unroll
      for(int c=0;c<4;c++){
        int bo = (c*16 + l15)*72 + ks*32 + g*8;
        short8 bh = *(const short8*)&Khs[bo];
        short8 bl = *(const short8*)&Kls[bo];
        acc[c] = __builtin_amdgcn_mfma_f32_16x16x32_bf16(ah, bh, acc[c], 0, 0, 0);
        acc[c] = __builtin_amdgcn_mfma_f32_16x16x32_bf16(ah, bl, acc[c], 0, 0, 0);
        acc[c] = __builtin_amdgcn_mfma_f32_16x16x32_bf16(al, bh, acc[c], 0, 0, 0);
      }
    }
  }
  const bool full = (ti > tj);
  const int qbase = q0 + w*16 + g*4;
  #pragma unroll
  for(int c=0;c<4;c++){
    int kcol = k0 + c*16 + l15;
    float cm = -INFINITY;
    #pragma unroll
    for(int j=0;j<4;j++){
      int q = qbase + j;
      float s = acc[c][j]*SCALE;
      bool valid = full || (q >= kcol);
      attn[((size_t)(b*S_) + q)*S_ + kcol] = valid ? s : 0.f;
      if(valid) cm = fmaxf(cm, s);
    }
    cred[w*4 + g][c*16 + l15] = cm;
  }
  __syncthreads();
  if(tid < 64){
    float m = cred[0][tid];
    #pragma unroll
    for(int gg=1;gg<16;gg++) m = fmaxf(m, cred[gg][tid]);
    atomicMax(&cmax[b*S_ + k0 + tid], enc_f32(m));
  }
}

// ---- exp + per-column partial sums (READ-ONLY: no store; pv recomputes p) ----
__global__ __launch_bounds__(256) void expsum_kernel(
    const float* __restrict__ attn, const unsigned* __restrict__ cmax,
    float* __restrict__ colpart)
{
  const int cj = blockIdx.x, ti = blockIdx.y, b = blockIdx.z;
  if(ti < 4*cj) return;                        // fully masked block
  __shared__ float part[4][256];
  const int tid = threadIdx.x;
  const int c4 = tid & 63, g = tid >> 6;
  const int q0 = ti*64, k0 = cj*256;
  const int kbase = k0 + c4*4;
  float mc[4];
  #pragma unroll
  for(int j=0;j<4;j++) mc[j] = dec_f32(cmax[b*S_ + kbase + j]);
  float sum[4] = {0.f,0.f,0.f,0.f};
  #pragma unroll 4
  for(int rr=0;rr<16;rr++){
    int q = q0 + g*16 + rr;
    size_t idx = ((size_t)(b*S_) + q)*S_ + kbase;
    float4 sv = *reinterpret_cast<const float4*>(&attn[idx]);
    sum[0] += (q >= kbase+0) ? __expf(sv.x - mc[0]) : 0.f;
    sum[1] += (q >= kbase+1) ? __expf(sv.y - mc[1]) : 0.f;
    sum[2] += (q >= kbase+2) ? __expf(sv.z - mc[2]) : 0.f;
    sum[3] += (q >= kbase+3) ? __expf(sv.w - mc[3]) : 0.f;
  }
  #pragma unroll
  for(int j=0;j<4;j++) part[g][c4*4+j] = sum[j];
  __syncthreads();
  {
    int k = k0 + tid;
    float tot = ((part[0][tid] + part[1][tid]) + part[2][tid]) + part[3][tid];
    colpart[((size_t)(b*S_) + k)*32 + ti] = tot;
  }
}

// ---- column reduce in fixed order -> reciprocal sums ----
__global__ __launch_bounds__(256) void colreduce_kernel(
    const float* __restrict__ colpart, float* __restrict__ rcol)
{
  int i = blockIdx.x*256 + threadIdx.x;  // 0..8191 = b*S + k
  if(i >= B_*S_) return;
  int k = i & (S_-1);
  int t0 = k >> 6;
  float s = 0.f;
  for(int t=t0; t<32; t++) s += colpart[(size_t)i*32 + t];
  rcol[i] = 1.0f / s;
}

// ---- fused PV (bf16x3 MFMA): p=exp(s-m)*rcol written to attn in place; partials out ----
__global__ __launch_bounds__(256) void pv_kernel(
    float* __restrict__ attn, const unsigned* __restrict__ cmax,
    const float* __restrict__ rcol,
    const unsigned short* __restrict__ Vth, const unsigned short* __restrict__ Vtl,
    float* __restrict__ part, int ns)
{
  __shared__ __align__(16) unsigned short sm[27648];  // Ah,Al [64][72]; Vh,Vl [128][72] = 54KB
  unsigned short* Ahs = sm;
  unsigned short* Als = sm + 4608;
  unsigned short* Vhs = sm + 9216;
  unsigned short* Vls = sm + 18432;
  const int b = blockIdx.z, tid = threadIdx.x;
  const int sp = blockIdx.y;
  const int w = tid >> 6, lane = tid & 63, l15 = lane & 15, g = lane >> 4;
  const int t = 31 - (int)blockIdx.x;              // heavy tiles first
  const int q0 = t*64;
  const int nch = t + 1;
  const int lo = (sp*nch)/ns, hi = ((sp+1)*nch)/ns;
  f32x4 acc[8] = {f32x4{0,0,0,0},f32x4{0,0,0,0},f32x4{0,0,0,0},f32x4{0,0,0,0},
                  f32x4{0,0,0,0},f32x4{0,0,0,0},f32x4{0,0,0,0},f32x4{0,0,0,0}};
  const int er = tid >> 4, ekq = (tid & 15) << 2;  // E quad: rows rr*16+er, cols ekq..+3
  for(int ch=lo; ch<hi; ++ch){
    const int k0c = ch*64;
    uint4 mu = *reinterpret_cast<const uint4*>(&cmax[b*S_ + k0c + ekq]);
    float4 r4 = *reinterpret_cast<const float4*>(&rcol[b*S_ + k0c + ekq]);
    float mc0 = dec_f32(mu.x), mc1 = dec_f32(mu.y), mc2 = dec_f32(mu.z), mc3 = dec_f32(mu.w);
    const bool diag = (ch == t);
    __syncthreads();                               // prev MFMA readers done
    #pragma unroll
    for(int rr=0; rr<4; ++rr){
      int row = rr*16 + er;
      size_t ea = ((size_t)(b*S_) + q0 + row)*S_ + k0c + ekq;
      float4 sv = *reinterpret_cast<const float4*>(&attn[ea]);
      float p0 = __expf(sv.x - mc0)*r4.x;
      float p1 = __expf(sv.y - mc1)*r4.y;
      float p2 = __expf(sv.z - mc2)*r4.z;
      float p3 = __expf(sv.w - mc3)*r4.w;
      if(diag){                                    // q>=k  <=>  row>=kc (q0==k0c)
        p0 = (row >= ekq+0) ? p0 : 0.f;
        p1 = (row >= ekq+1) ? p1 : 0.f;
        p2 = (row >= ekq+2) ? p2 : 0.f;
        p3 = (row >= ekq+3) ? p3 : 0.f;
      }
      float4 pv4 = {p0,p1,p2,p3};
      *reinterpret_cast<float4*>(&attn[ea]) = pv4; // normalized attention (final output)
      unsigned short h0=bf16rne(p0), h1=bf16rne(p1), h2=bf16rne(p2), h3=bf16rne(p3);
      *(us4*)&Ahs[row*72 + ekq] = us4{h0,h1,h2,h3};
      *(us4*)&Als[row*72 + ekq] = us4{ bf16rne(p0-bf16tof(h0)), bf16rne(p1-bf16tof(h1)),
                                       bf16rne(p2-bf16tof(h2)), bf16rne(p3-bf16tof(h3)) };
    }
    #pragma unroll
    for(int v=0; v<4; ++v){                        // V stage: [128 d][64 k] hi/lo (1024 chunks)
      int idx = v*256 + tid;
      int d = idx >> 3, c8 = (idx & 7) << 3;
      size_t ga = (size_t)(b*DK_ + d)*S_ + k0c + c8;
      *(short8*)&Vhs[d*72 + c8] = *(const short8*)&Vth[ga];
      *(short8*)&Vls[d*72 + c8] = *(const short8*)&Vtl[ga];
    }
    __syncthreads();
    #pragma unroll
    for(int ks=0; ks<2; ++ks){
      int ao = (w*16 + l15)*72 + ks*32 + g*8;
      short8 ah = *(const short8*)&Ahs[ao];
      short8 al = *(const short8*)&Als[ao];
      #pragma unroll
      for(int c=0;c<8;c++){
        int bo = (c*16 + l15)*72 + ks*32 + g*8;
        short8 bh = *(const short8*)&Vhs[bo];
        short8 bl = *(const short8*)&Vls[bo];
        acc[c] = __builtin_amdgcn_mfma_f32_16x16x32_bf16(ah, bh, acc[c], 0, 0, 0);
        acc[c] = __builtin_amdgcn_mfma_f32_16x16x32_bf16(ah, bl, acc[c], 0, 0, 0);
        acc[c] = __builtin_amdgcn_mfma_f32_16x16x32_bf16(al, bh, acc[c], 0, 0, 0);
      }
    }
  }
  float* pout = part + (((size_t)(sp*B_ + b))*S_ + q0)*DK_;   // 64 x 128 region
  #pragma unroll
  for(int c=0;c<8;c++){
    #pragma unroll
    for(int j=0;j<4;j++){
      int qrow = w*16 + g*4 + j;
      pout[(size_t)qrow*DK_ + c*16 + l15] = acc[c][j];
    }
  }
}

// ---- sum split-K partials in fixed order ----
__global__ __launch_bounds__(256) void pvreduce_kernel(
    const float* __restrict__ part, float* __restrict__ out, int ns)
{
  const int N4 = (B_*S_*DK_)/4;   // 262144 float4
  int i = blockIdx.x*256 + threadIdx.x;
  if(i >= N4) return;
  const float4* p = reinterpret_cast<const float4*>(part);
  float4 a = p[i];
  for(int s=1; s<ns; ++s){
    float4 q = p[(size_t)s*N4 + i];
    a.x += q.x; a.y += q.y; a.z += q.z; a.w += q.w;
  }
  reinterpret_cast<float4*>(out)[i] = a;
}

extern "C" void kernel_launch(void* const* d_in, const int* in_sizes, int n_in,
                              void* d_out, int out_size, void* d_ws, size_t ws_size,
                              hipStream_t stream)
{
  (void)in_sizes; (void)n_in; (void)out_size;
  const float* X  = (const float*)d_in[0];
  const float* Wq = (const float*)d_in[1];
  const float* Wk = (const float*)d_in[2];
  const float* Wv = (const float*)d_in[3];
  float* out  = (float*)d_out;
  float* attn = out + (size_t)B_*S_*DK_;            // attention output region (67MB)

  // X bf16 hi/lo images live INSIDE the attn region (dead once scores runs)
  unsigned short* Xth = (unsigned short*)attn;            // 16MB
  unsigned short* Xtl = Xth + (size_t)8388608;            // 16MB

  float* ws = (float*)d_ws;
  unsigned* cmax = (unsigned*)ws;                    // [8192]
  float* rcol    = ws + 8192;                        // [8192]
  float* colpart = ws + 16384;                       // [262144]
  unsigned short* Wth = (unsigned short*)(ws + 278528);   // [3][32][5120] shorts
  unsigned short* Wtl = (unsigned short*)(ws + 524288);
  unsigned short* Qh  = (unsigned short*)(ws + 770048);   // [8192][128] shorts each
  unsigned short* Ql  = (unsigned short*)(ws + 1294336);
  unsigned short* Kh  = (unsigned short*)(ws + 1818624);
  unsigned short* Kl  = (unsigned short*)(ws + 2342912);
  unsigned short* Vth = (unsigned short*)(ws + 2867200);  // [4][128][2048] shorts each
  unsigned short* Vtl = (unsigned short*)(ws + 3391488);
  const size_t base = 3915776;                       // floats used so far
  float* part    = ws + base;                        // [ns][4][2048][128]

  int ns = 4;
  if(ws_size < (base + (size_t)4*1048576)*sizeof(float)) ns = 2;
  if(ws_size < (base + (size_t)2*1048576)*sizeof(float)) ns = 1;

  init_kernel<<<dim3(32), dim3(256), 0, stream>>>(cmax);
  xconv_kernel<<<dim3(8192), dim3(256), 0, stream>>>(X, Xth, Xtl);
  wconv_kernel<<<dim3(32,3), dim3(256), 0, stream>>>(Wq, Wk, Wv, Wth, Wtl);
  qkv_mfma_kernel<<<dim3(256,3), dim3(256), 0, stream>>>(Xth, Xtl, Wth, Wtl, Qh, Ql, Kh, Kl, Vth, Vtl);
  scores_kernel<<<dim3(32,32,4), dim3(256), 0, stream>>>(Qh, Ql, Kh, Kl, attn, cmax);
  expsum_kernel<<<dim3(8,32,4), dim3(256), 0, stream>>>(attn, cmax, colpart);
  colreduce_kernel<<<dim3(32), dim3(256), 0, stream>>>(colpart, rcol);
  pv_kernel<<<dim3(32,ns,4), dim3(256), 0, stream>>>(attn, cmax, rcol, Vth, Vtl, part, ns);
  pvreduce_kernel<<<dim3(1024), dim3(256), 0, stream>>>(part, out, ns);
}

// Round 16
// 121.335 us; speedup vs baseline: 1.0280x; 1.0280x over previous
//
#include <hip/hip_runtime.h>
#include <math.h>
#include <stdint.h>

#define B_ 4
#define S_ 2048
#define DM_ 1024
#define DK_ 128

static constexpr float SCALE = 0.08838834764831845f; // 1/sqrt(128)

typedef __attribute__((ext_vector_type(8))) short short8;
typedef __attribute__((ext_vector_type(4))) float f32x4;
typedef __attribute__((ext_vector_type(4))) unsigned short us4;

__device__ __forceinline__ unsigned short bf16rne(float f){
  unsigned u = __float_as_uint(f);
  unsigned r = (u + 0x7FFFu + ((u>>16)&1u)) >> 16;
  return (unsigned short)r;
}
__device__ __forceinline__ float bf16tof(unsigned short h){
  return __uint_as_float((unsigned)h << 16);
}
// async global->LDS, 16B per lane; LDS dest = wave-uniform base + lane*16
__device__ __forceinline__ void gload16(const void* g, void* l){
  __builtin_amdgcn_global_load_lds(
      (const __attribute__((address_space(1))) void*)g,
      (__attribute__((address_space(3))) void*)l, 16, 0, 0);
}

// ---- X pre-convert: f32 [8192][1024] -> bf16 hi/lo MFMA-fragment image ----
__global__ __launch_bounds__(256) void xconv_kernel(
    const float* __restrict__ X,
    unsigned short* __restrict__ Xth, unsigned short* __restrict__ Xtl)
{
  const int kt = blockIdx.x & 31, mb = blockIdx.x >> 5;
  const int tid = threadIdx.x;
  const int unit = tid & 127, half = tid >> 7;
  const int g = unit >> 5, row = unit & 31;
  const float* src = X + (size_t)(mb*32 + row)*DM_ + kt*32 + g*8;
  float4 a = *reinterpret_cast<const float4*>(src);
  float4 b = *reinterpret_cast<const float4*>(src + 4);
  unsigned short* dst = (half ? Xtl : Xth) + ((size_t)(mb*32 + kt)*128 + unit)*8;
  if(half == 0){
    us4 h0 = {bf16rne(a.x),bf16rne(a.y),bf16rne(a.z),bf16rne(a.w)};
    us4 h1 = {bf16rne(b.x),bf16rne(b.y),bf16rne(b.z),bf16rne(b.w)};
    *(us4*)dst = h0; *(us4*)(dst+4) = h1;
  } else {
    us4 l0 = {bf16rne(a.x - bf16tof(bf16rne(a.x))), bf16rne(a.y - bf16tof(bf16rne(a.y))),
              bf16rne(a.z - bf16tof(bf16rne(a.z))), bf16rne(a.w - bf16tof(bf16rne(a.w)))};
    us4 l1 = {bf16rne(b.x - bf16tof(bf16rne(b.x))), bf16rne(b.y - bf16tof(bf16rne(b.y))),
              bf16rne(b.z - bf16tof(bf16rne(b.z))), bf16rne(b.w - bf16tof(bf16rne(b.w)))};
    *(us4*)dst = l0; *(us4*)(dst+4) = l1;
  }
}

// ---- W pre-convert: f32 [1024][128] -> bf16 hi/lo, pre-tiled [32 t][col][40] ----
__global__ __launch_bounds__(256) void wconv_kernel(
    const float* __restrict__ Wq, const float* __restrict__ Wk, const float* __restrict__ Wv,
    unsigned short* __restrict__ Wth, unsigned short* __restrict__ Wtl)
{
  const int t = blockIdx.x;       // k-tile 0..31
  const int which = blockIdx.y;   // 0..2
  const float* W = (which==0) ? Wq : ((which==1) ? Wk : Wv);
  const int tid = threadIdx.x;
  const size_t obase = ((size_t)which*32 + t)*5120;
  #pragma unroll
  for(int it=0; it<2; ++it){
    int idx = tid + 256*it;       // 0..511 -> (col, g)
    int col = idx & 127, g = idx >> 7;
    unsigned short hs[8], ls[8];
    #pragma unroll
    for(int j=0;j<8;j++){
      float f = W[(size_t)(t*32 + g*8 + j)*DK_ + col];
      unsigned short h = bf16rne(f);
      hs[j] = h;
      ls[j] = bf16rne(f - bf16tof(h));
    }
    size_t o = obase + (size_t)col*40 + g*8;
    *(us4*)&Wth[o]   = us4{hs[0],hs[1],hs[2],hs[3]};
    *(us4*)&Wth[o+4] = us4{hs[4],hs[5],hs[6],hs[7]};
    *(us4*)&Wtl[o]   = us4{ls[0],ls[1],ls[2],ls[3]};
    *(us4*)&Wtl[o+4] = us4{ls[4],ls[5],ls[6],ls[7]};
  }
}

// ---- QKV GEMM v8: bf16x3 MFMA, M=32; A and B via global_load_lds dbuf; 1 barrier/tile ----
__global__ __launch_bounds__(256) void qkv_mfma_kernel(
    const unsigned short* __restrict__ Xth, const unsigned short* __restrict__ Xtl,
    const unsigned short* __restrict__ Wth, const unsigned short* __restrict__ Wtl,
    unsigned short* __restrict__ Qh, unsigned short* __restrict__ Ql,
    unsigned short* __restrict__ Kh, unsigned short* __restrict__ Kl,
    unsigned short* __restrict__ Vth, unsigned short* __restrict__ Vtl)
{
  __shared__ __align__(16) unsigned char smem[49152];
  const int tid = threadIdx.x;
  const int w = tid >> 6, lane = tid & 63;
  const int l15 = lane & 15, g = lane >> 4;
  const int which = blockIdx.y;
  const int m0 = blockIdx.x * 32;
  const int mb = blockIdx.x;
  const unsigned char* Wh8 = (const unsigned char*)(Wth + (size_t)which*32*5120);
  const unsigned char* Wl8 = (const unsigned char*)(Wtl + (size_t)which*32*5120);
  const unsigned short* Asrc = ((w < 2) ? Xth : Xtl) + (size_t)(mb*32)*1024 + (w & 1)*512 + lane*8;
  const unsigned Adst = (unsigned)((w & 1)*1024) + ((w < 2) ? 0u : 2048u);

  gload16(Asrc, smem + Adst);
  #pragma unroll
  for(int ii=0; ii<5; ++ii){
    int i = w + 4*ii;
    const unsigned char* src = (i<10) ? (Wh8 + i*1024) : (Wl8 + (i-10)*1024);
    unsigned dst = 8192u + ((i<10) ? (unsigned)i*1024u : 10240u + (unsigned)(i-10)*1024u);
    gload16(src + lane*16, smem + dst);
  }

  f32x4 acc[4] = {f32x4{0,0,0,0},f32x4{0,0,0,0},f32x4{0,0,0,0},f32x4{0,0,0,0}};
  const int r = w >> 1, c0 = (w & 1)*4;
  const int aoff = (g*32 + r*16 + l15)*8;
  int buf = 0;
  for(int t=0; t<32; ++t){
    __syncthreads();
    if(t+1 < 32){
      gload16(Asrc + (size_t)(t+1)*1024, smem + (buf^1)*4096 + Adst);
      const unsigned char* WhT = Wh8 + (size_t)(t+1)*10240;
      const unsigned char* WlT = Wl8 + (size_t)(t+1)*10240;
      unsigned bbase = 8192u + (unsigned)(buf^1)*20480u;
      #pragma unroll
      for(int ii=0; ii<5; ++ii){
        int i = w + 4*ii;
        const unsigned char* src = (i<10) ? (WhT + i*1024) : (WlT + (i-10)*1024);
        unsigned dst = bbase + ((i<10) ? (unsigned)i*1024u : 10240u + (unsigned)(i-10)*1024u);
        gload16(src + lane*16, smem + dst);
      }
    }
    const unsigned short* Ab = (const unsigned short*)(smem + buf*4096);
    const unsigned short* Bhc = (const unsigned short*)(smem + 8192 + buf*20480);
    const unsigned short* Blc = Bhc + 5120;
    short8 ah = *(const short8*)&Ab[aoff];
    short8 al = *(const short8*)&Ab[1024 + aoff];
    #pragma unroll
    for(int c=0;c<4;c++){
      int boff = ((c0+c)*16 + l15)*40 + g*8;
      short8 bh = *(const short8*)&Bhc[boff];
      short8 bl = *(const short8*)&Blc[boff];
      acc[c] = __builtin_amdgcn_mfma_f32_16x16x32_bf16(ah, bh, acc[c], 0, 0, 0);
      acc[c] = __builtin_amdgcn_mfma_f32_16x16x32_bf16(ah, bl, acc[c], 0, 0, 0);
      acc[c] = __builtin_amdgcn_mfma_f32_16x16x32_bf16(al, bh, acc[c], 0, 0, 0);
    }
    buf ^= 1;
  }
  const int b = m0 >> 11;
  const int orow0 = g*4;
  if(which != 2){
    unsigned short* Oh = (which==0) ? Qh : Kh;
    unsigned short* Ol = (which==0) ? Ql : Kl;
    #pragma unroll
    for(int c=0;c<4;c++){
      int col = (c0+c)*16 + l15;
      #pragma unroll
      for(int j=0;j<4;j++){
        float f = acc[c][j];
        unsigned short h = bf16rne(f);
        unsigned short lo = bf16rne(f - bf16tof(h));
        size_t o = (size_t)(m0 + r*16 + orow0 + j)*DK_ + col;
        Oh[o] = h; Ol[o] = lo;
      }
    }
  } else {
    __syncthreads();
    float* Tmp = (float*)smem;                 // [32][133]
    #pragma unroll
    for(int c=0;c<4;c++){
      int col = (c0+c)*16 + l15;
      #pragma unroll
      for(int j=0;j<4;j++)
        Tmp[(r*16 + orow0 + j)*133 + col] = acc[c][j];
    }
    __syncthreads();
    const int s0 = m0 & (S_-1);
    #pragma unroll
    for(int l2=0;l2<16;l2++){
      int p = tid + 256*l2;
      int d = p >> 5, rr = p & 31;
      float f = Tmp[rr*133 + d];
      unsigned short h = bf16rne(f);
      Vth[(size_t)(b*DK_ + d)*S_ + s0 + rr] = h;
      Vtl[(size_t)(b*DK_ + d)*S_ + s0 + rr] = bf16rne(f - bf16tof(h));
    }
  }
}

// ---- scores via bf16x3 MFMA: raw s (masked=0) -> attn; per-tile (max, exp-sum) partials ----
__global__ __launch_bounds__(256) void scores_kernel(
    const unsigned short* __restrict__ Qh, const unsigned short* __restrict__ Ql,
    const unsigned short* __restrict__ Kh, const unsigned short* __restrict__ Kl,
    float* __restrict__ attn, float* __restrict__ cmaxpart, float* __restrict__ csumpart)
{
  const int tj = blockIdx.x, ti = blockIdx.y, b = blockIdx.z;
  const int tid = threadIdx.x;
  const int q0 = ti*64, k0 = tj*64;
  if(tj > ti){                                 // upper triangle: zero-fill tile
    float4 z = {0.f,0.f,0.f,0.f};
    #pragma unroll
    for(int l=0;l<4;l++){
      int p = tid + 256*l;
      int r = p >> 4, c = (p & 15) << 2;
      *reinterpret_cast<float4*>(&attn[((size_t)(b*S_) + q0 + r)*S_ + k0 + c]) = z;
    }
    return;
  }
  __shared__ __align__(16) unsigned short sm[18432];   // 4 x [64][72]
  __shared__ float cred[16][64];
  __shared__ float csum[16][64];
  __shared__ float maxsh[64];
  unsigned short* Qhs = sm;
  unsigned short* Qls = sm + 4608;
  unsigned short* Khs = sm + 9216;
  unsigned short* Kls = sm + 13824;
  const int w = tid >> 6, lane = tid & 63, l15 = lane & 15, g = lane >> 4;
  f32x4 acc[4] = {f32x4{0,0,0,0},f32x4{0,0,0,0},f32x4{0,0,0,0},f32x4{0,0,0,0}};
  for(int kh=0; kh<2; ++kh){
    __syncthreads();                           // prev compute readers done
    #pragma unroll
    for(int l=0;l<2;l++){                      // stage 4 tiles (this K-half)
      int p = tid + 256*l;
      int row = p >> 3, cc = p & 7;
      size_t gq = (size_t)(b*S_ + q0 + row)*DK_ + kh*64 + cc*8;
      size_t gk = (size_t)(b*S_ + k0 + row)*DK_ + kh*64 + cc*8;
      int lo_ = row*72 + cc*8;
      *(short8*)&Qhs[lo_] = *(const short8*)&Qh[gq];
      *(short8*)&Qls[lo_] = *(const short8*)&Ql[gq];
      *(short8*)&Khs[lo_] = *(const short8*)&Kh[gk];
      *(short8*)&Kls[lo_] = *(const short8*)&Kl[gk];
    }
    __syncthreads();
    #pragma unroll
    for(int ks=0; ks<2; ++ks){                 // 2 x K=32 per half
      int ao = (w*16 + l15)*72 + ks*32 + g*8;
      short8 ah = *(const short8*)&Qhs[ao];
      short8 al = *(const short8*)&Qls[ao];
      #pragma unroll
      for(int c=0;c<4;c++){
        int bo = (c*16 + l15)*72 + ks*32 + g*8;
        short8 bh = *(const short8*)&Khs[bo];
        short8 bl = *(const short8*)&Kls[bo];
        acc[c] = __builtin_amdgcn_mfma_f32_16x16x32_bf16(ah, bh, acc[c], 0, 0, 0);
        acc[c] = __builtin_amdgcn_mfma_f32_16x16x32_bf16(ah, bl, acc[c], 0, 0, 0);
        acc[c] = __builtin_amdgcn_mfma_f32_16x16x32_bf16(al, bh, acc[c], 0, 0, 0);
      }
    }
  }
  const bool full = (ti > tj);
  const int qbase = q0 + w*16 + g*4;
  // pass 1: store raw s (masked=0) + per-lane column max
  #pragma unroll
  for(int c=0;c<4;c++){
    int kcol = k0 + c*16 + l15;
    float cm = -INFINITY;
    #pragma unroll
    for(int j=0;j<4;j++){
      int q = qbase + j;
      float s = acc[c][j]*SCALE;
      bool valid = full || (q >= kcol);
      attn[((size_t)(b*S_) + q)*S_ + kcol] = valid ? s : 0.f;
      if(valid) cm = fmaxf(cm, s);
    }
    cred[w*4 + g][c*16 + l15] = cm;
  }
  __syncthreads();
  if(tid < 64){
    float m = cred[0][tid];
    #pragma unroll
    for(int gg=1;gg<16;gg++) m = fmaxf(m, cred[gg][tid]);
    maxsh[tid] = m;
    cmaxpart[((size_t)(b*S_) + k0 + tid)*32 + ti] = m;   // per-tile column max
  }
  __syncthreads();
  // pass 2: per-lane exp-sum partials against the tile max
  #pragma unroll
  for(int c=0;c<4;c++){
    int col = c*16 + l15;
    int kcol = k0 + col;
    float mcol = maxsh[col];
    float ps = 0.f;
    #pragma unroll
    for(int j=0;j<4;j++){
      int q = qbase + j;
      bool valid = full || (q >= kcol);
      if(valid) ps += __expf(acc[c][j]*SCALE - mcol);
    }
    csum[w*4 + g][col] = ps;
  }
  __syncthreads();
  if(tid < 64){
    float s = 0.f;
    #pragma unroll
    for(int gg=0;gg<16;gg++) s += csum[gg][tid];
    csumpart[((size_t)(b*S_) + k0 + tid)*32 + ti] = s;   // per-tile exp-sum
  }
}

// ---- column flash-reduce in fixed tile order -> final max + reciprocal sums ----
__global__ __launch_bounds__(256) void colreduce_kernel(
    const float* __restrict__ cmaxpart, const float* __restrict__ csumpart,
    float* __restrict__ cmaxf, float* __restrict__ rcol)
{
  int i = blockIdx.x*256 + threadIdx.x;  // 0..8191 = b*S + k
  if(i >= B_*S_) return;
  int k = i & (S_-1);
  int t0 = k >> 6;
  float M = -INFINITY;
  for(int t=t0; t<32; t++) M = fmaxf(M, cmaxpart[(size_t)i*32 + t]);
  float s = 0.f;
  for(int t=t0; t<32; t++) s += csumpart[(size_t)i*32 + t] * __expf(cmaxpart[(size_t)i*32 + t] - M);
  cmaxf[i] = M;
  rcol[i] = 1.0f / s;
}

// ---- fused PV (bf16x3 MFMA): p=exp(s-M)*rcol written to attn in place; partials out ----
__global__ __launch_bounds__(256) void pv_kernel(
    float* __restrict__ attn, const float* __restrict__ cmaxf,
    const float* __restrict__ rcol,
    const unsigned short* __restrict__ Vth, const unsigned short* __restrict__ Vtl,
    float* __restrict__ part, int ns)
{
  __shared__ __align__(16) unsigned short sm[27648];  // Ah,Al [64][72]; Vh,Vl [128][72]
  unsigned short* Ahs = sm;
  unsigned short* Als = sm + 4608;
  unsigned short* Vhs = sm + 9216;
  unsigned short* Vls = sm + 18432;
  const int b = blockIdx.z, tid = threadIdx.x;
  const int sp = blockIdx.y;
  const int w = tid >> 6, lane = tid & 63, l15 = lane & 15, g = lane >> 4;
  const int t = 31 - (int)blockIdx.x;              // heavy tiles first
  const int q0 = t*64;
  const int nch = t + 1;
  const int lo = (sp*nch)/ns, hi = ((sp+1)*nch)/ns;
  f32x4 acc[8] = {f32x4{0,0,0,0},f32x4{0,0,0,0},f32x4{0,0,0,0},f32x4{0,0,0,0},
                  f32x4{0,0,0,0},f32x4{0,0,0,0},f32x4{0,0,0,0},f32x4{0,0,0,0}};
  const int er = tid >> 4, ekq = (tid & 15) << 2;  // E quad: rows rr*16+er, cols ekq..+3
  for(int ch=lo; ch<hi; ++ch){
    const int k0c = ch*64;
    float4 m4 = *reinterpret_cast<const float4*>(&cmaxf[b*S_ + k0c + ekq]);
    float4 r4 = *reinterpret_cast<const float4*>(&rcol[b*S_ + k0c + ekq]);
    const bool diag = (ch == t);
    __syncthreads();                               // prev MFMA readers done
    #pragma unroll
    for(int rr=0; rr<4; ++rr){
      int row = rr*16 + er;
      size_t ea = ((size_t)(b*S_) + q0 + row)*S_ + k0c + ekq;
      float4 sv = *reinterpret_cast<const float4*>(&attn[ea]);
      float p0 = __expf(sv.x - m4.x)*r4.x;
      float p1 = __expf(sv.y - m4.y)*r4.y;
      float p2 = __expf(sv.z - m4.z)*r4.z;
      float p3 = __expf(sv.w - m4.w)*r4.w;
      if(diag){                                    // q>=k  <=>  row>=kc (q0==k0c)
        p0 = (row >= ekq+0) ? p0 : 0.f;
        p1 = (row >= ekq+1) ? p1 : 0.f;
        p2 = (row >= ekq+2) ? p2 : 0.f;
        p3 = (row >= ekq+3) ? p3 : 0.f;
      }
      float4 pv4 = {p0,p1,p2,p3};
      *reinterpret_cast<float4*>(&attn[ea]) = pv4; // normalized attention (final output)
      unsigned short h0=bf16rne(p0), h1=bf16rne(p1), h2=bf16rne(p2), h3=bf16rne(p3);
      *(us4*)&Ahs[row*72 + ekq] = us4{h0,h1,h2,h3};
      *(us4*)&Als[row*72 + ekq] = us4{ bf16rne(p0-bf16tof(h0)), bf16rne(p1-bf16tof(h1)),
                                       bf16rne(p2-bf16tof(h2)), bf16rne(p3-bf16tof(h3)) };
    }
    #pragma unroll
    for(int v=0; v<4; ++v){                        // V stage: [128 d][64 k] hi/lo
      int idx = v*256 + tid;
      int d = idx >> 3, c8 = (idx & 7) << 3;
      size_t ga = (size_t)(b*DK_ + d)*S_ + k0c + c8;
      *(short8*)&Vhs[d*72 + c8] = *(const short8*)&Vth[ga];
      *(short8*)&Vls[d*72 + c8] = *(const short8*)&Vtl[ga];
    }
    __syncthreads();
    #pragma unroll
    for(int ks=0; ks<2; ++ks){
      int ao = (w*16 + l15)*72 + ks*32 + g*8;
      short8 ah = *(const short8*)&Ahs[ao];
      short8 al = *(const short8*)&Als[ao];
      #pragma unroll
      for(int c=0;c<8;c++){
        int bo = (c*16 + l15)*72 + ks*32 + g*8;
        short8 bh = *(const short8*)&Vhs[bo];
        short8 bl = *(const short8*)&Vls[bo];
        acc[c] = __builtin_amdgcn_mfma_f32_16x16x32_bf16(ah, bh, acc[c], 0, 0, 0);
        acc[c] = __builtin_amdgcn_mfma_f32_16x16x32_bf16(ah, bl, acc[c], 0, 0, 0);
        acc[c] = __builtin_amdgcn_mfma_f32_16x16x32_bf16(al, bh, acc[c], 0, 0, 0);
      }
    }
  }
  float* pout = part + (((size_t)(sp*B_ + b))*S_ + q0)*DK_;   // 64 x 128 region
  #pragma unroll
  for(int c=0;c<8;c++){
    #pragma unroll
    for(int j=0;j<4;j++){
      int qrow = w*16 + g*4 + j;
      pout[(size_t)qrow*DK_ + c*16 + l15] = acc[c][j];
    }
  }
}

// ---- sum split-K partials in fixed order ----
__global__ __launch_bounds__(256) void pvreduce_kernel(
    const float* __restrict__ part, float* __restrict__ out, int ns)
{
  const int N4 = (B_*S_*DK_)/4;   // 262144 float4
  int i = blockIdx.x*256 + threadIdx.x;
  if(i >= N4) return;
  const float4* p = reinterpret_cast<const float4*>(part);
  float4 a = p[i];
  for(int s=1; s<ns; ++s){
    float4 q = p[(size_t)s*N4 + i];
    a.x += q.x; a.y += q.y; a.z += q.z; a.w += q.w;
  }
  reinterpret_cast<float4*>(out)[i] = a;
}

extern "C" void kernel_launch(void* const* d_in, const int* in_sizes, int n_in,
                              void* d_out, int out_size, void* d_ws, size_t ws_size,
                              hipStream_t stream)
{
  (void)in_sizes; (void)n_in; (void)out_size;
  const float* X  = (const float*)d_in[0];
  const float* Wq = (const float*)d_in[1];
  const float* Wk = (const float*)d_in[2];
  const float* Wv = (const float*)d_in[3];
  float* out  = (float*)d_out;
  float* attn = out + (size_t)B_*S_*DK_;            // attention output region (64MB)

  // X bf16 hi/lo images live INSIDE the attn region (dead once scores runs)
  unsigned short* Xth = (unsigned short*)attn;            // 16MB
  unsigned short* Xtl = Xth + (size_t)8388608;            // 16MB

  float* ws = (float*)d_ws;
  float* cmaxf    = ws;                              // [8192]
  float* rcol     = ws + 8192;                       // [8192]
  float* csumpart = ws + 16384;                      // [8192*32]
  float* cmaxpart = ws + 278528;                     // [8192*32]
  unsigned short* Wth = (unsigned short*)(ws + 540672);   // [3][32][5120] shorts
  unsigned short* Wtl = (unsigned short*)(ws + 786432);
  unsigned short* Qh  = (unsigned short*)(ws + 1032192);  // [8192][128] shorts each
  unsigned short* Ql  = (unsigned short*)(ws + 1556480);
  unsigned short* Kh  = (unsigned short*)(ws + 2080768);
  unsigned short* Kl  = (unsigned short*)(ws + 2605056);
  unsigned short* Vth = (unsigned short*)(ws + 3129344);  // [4][128][2048] shorts each
  unsigned short* Vtl = (unsigned short*)(ws + 3653632);
  const size_t base = 4177920;                       // floats used so far
  float* part    = ws + base;                        // [ns][4][2048][128]

  int ns = 4;
  if(ws_size < (base + (size_t)4*1048576)*sizeof(float)) ns = 2;
  if(ws_size < (base + (size_t)2*1048576)*sizeof(float)) ns = 1;

  xconv_kernel<<<dim3(8192), dim3(256), 0, stream>>>(X, Xth, Xtl);
  wconv_kernel<<<dim3(32,3), dim3(256), 0, stream>>>(Wq, Wk, Wv, Wth, Wtl);
  qkv_mfma_kernel<<<dim3(256,3), dim3(256), 0, stream>>>(Xth, Xtl, Wth, Wtl, Qh, Ql, Kh, Kl, Vth, Vtl);
  scores_kernel<<<dim3(32,32,4), dim3(256), 0, stream>>>(Qh, Ql, Kh, Kl, attn, cmaxpart, csumpart);
  colreduce_kernel<<<dim3(32), dim3(256), 0, stream>>>(cmaxpart, csumpart, cmaxf, rcol);
  pv_kernel<<<dim3(32,ns,4), dim3(256), 0, stream>>>(attn, cmaxf, rcol, Vth, Vtl, part, ns);
  pvreduce_kernel<<<dim3(1024), dim3(256), 0, stream>>>(part, out, ns);
}